// Round 6
// baseline (475.050 us; speedup 1.0000x reference)
//
#include <hip/hip_runtime.h>

#define NKER 84
#define NCH 9
#define SEQ 2048
#define NBATCH 64
#define NDIL 26
#define NFTOT 9996
#define MAXNF 15
#define NSLOT 12
#define NXCD 8
#define WPB 4                    // waves per block (4 slots fused per workgroup)
#define NGRP (NSLOT / WPB)       // 3 slot-groups

// Static MiniRocket config for SEQ_LEN=2048, NUM_FEATURES=10000 (replicates numpy float64 logspace)
static constexpr int DILS[NDIL]   = {1,2,3,4,5,7,8,10,12,14,17,20,25,29,35,42,51,61,73,87,104,125,149,178,213,255};
static constexpr int NFDS[NDIL]   = {15,12,4,4,8,4,4,4,4,4,4,4,4,4,4,4,4,4,3,3,3,3,3,3,3,3};
static constexpr int CBASES[NDIL] = {0,1260,2268,2604,2940,3612,3948,4284,4620,4956,5292,5628,5964,6300,6636,6972,7308,7644,7980,8232,8484,8736,8988,9240,9492,9744};

// 2-float vector with 4-byte alignment: legal at odd dword offsets; compiler
// emits ds_read_b64 (aligned) or ds_read2_b32 offset0/offset1 (unaligned) —
// one DS instruction for two consecutive taps' elements either way.
// (Round-1/2 lesson: the b128 quad variant raised bank conflicts 3.7x and its
// register pressure triggered a 400MB scratch-spill catastrophe — stay at x2.)
typedef float f32x2u __attribute__((ext_vector_type(2), aligned(4)));

// Force a (known-uniform) float into an SGPR. v_fma/v_cmp accept one SGPR
// operand at full rate, so wave-uniform constants (w, bias) cost 0 VGPRs.
__device__ __forceinline__ float uniform_f(float v) {
    return __builtin_bit_cast(float, __builtin_amdgcn_readfirstlane(__builtin_bit_cast(int, v)));
}

template <int I>
__device__ __forceinline__ void body(const float* __restrict__ kw,
                                     const float* __restrict__ cc,
                                     const float* __restrict__ bias,
                                     float* __restrict__ out,
                                     const float* __restrict__ xb,   // x + b*NCH*SEQ
                                     float* __restrict__ y,          // this wave's private 8KB LDS slice
                                     int b, int slot, int lane) {
    constexpr int D = DILS[I];
    constexpr int NF = NFDS[I];
    constexpr int P = 4 * D;
    constexpr int PAD1 = I & 1;
    constexpr int CBASE = CBASES[I];
    constexpr int RANGE = SEQ - 2 * P;          // valid-region length (>0 for all D)
    // full-range loop split (compile-time): interior j has all taps in [0, SEQ) for every lane
    constexpr int JLO = (P + 63) / 64;                      // first fully-interior 64-iter
    constexpr int JHI = (SEQ - P - 64) / 64;                // last fully-interior 64-iter (incl)
    constexpr int NI  = (JHI + 1 > JLO) ? (JHI + 1 - JLO) : 0;   // # interior 64-iters
    constexpr int NI2 = NI / 2;                             // 128-el pair-iters
    constexpr bool IBR = (NI & 1) != 0;                     // one bridge 64-iter
    constexpr int JT0 = (JHI + 1 > JLO) ? (JHI + 1) : JLO;  // start of trailing boundary
    // valid-region decomposition: pairs + optional 64-bridge + clamped partial
    constexpr int MV2 = RANGE / 128;
    constexpr int TV1 = (RANGE - MV2 * 128) / 64;           // 0 or 1
    constexpr int REM = RANGE - MV2 * 128 - TV1 * 64;       // 0..63

    const float4* __restrict__ xb4 = (const float4*)xb;     // [NCH][SEQ/4]

    for (int k = slot; k < NKER; k += NSLOT) {
        // ---- per-kernel config (wave-uniform scalars) ----
        int mb = 0;
        for (int c = 0; c < NCH; ++c)
            if (cc[(I * NCH + c) * NKER + k] != 0.0f) mb |= (1 << c);
        mb = __builtin_amdgcn_readfirstlane(mb);

        int j0 = -1, j1 = -1, j2 = -1, no = 0;
        for (int j = 0; j < 9; ++j) {
            if (kw[k * 9 + j] > 0.0f) {
                if (no == 0) j0 = j; else if (no == 1) j1 = j; else j2 = j;
                ++no;
            }
        }
        j0 = __builtin_amdgcn_readfirstlane(j0);
        j1 = __builtin_amdgcn_readfirstlane(j1);
        j2 = __builtin_amdgcn_readfirstlane(j2);

        // tap weights and bias thresholds: wave-uniform -> force into SGPRs
        // (rounds 3-5: keeps the allocator under the 128-VGPR occupancy boundary).
        float w[9];
#pragma unroll
        for (int jj = 0; jj < 9; ++jj)
            w[jj] = uniform_f((jj == j0 || jj == j1 || jj == j2) ? 2.0f : -1.0f);

        float bs[NF];
#pragma unroll
        for (int f = 0; f < NF; ++f)
            bs[f] = uniform_f(bias[(I * NKER + k) * MAXNF + f]);

        // ---- build y[t] = sum of masked channels, two half-SEQ passes ----
#pragma unroll
        for (int h = 0; h < 2; ++h) {
            float4 acc[SEQ / 512];
#pragma unroll
            for (int it = 0; it < SEQ / 512; ++it)
                acc[it] = make_float4(0.f, 0.f, 0.f, 0.f);
#pragma unroll
            for (int c = 0; c < NCH; ++c) {
                if (mb & (1 << c)) {
#pragma unroll
                    for (int it = 0; it < SEQ / 512; ++it) {
                        float4 v = xb4[c * (SEQ / 4) + h * (SEQ / 8) + it * 64 + lane];
                        acc[it].x += v.x; acc[it].y += v.y; acc[it].z += v.z; acc[it].w += v.w;
                    }
                }
            }
#pragma unroll
            for (int it = 0; it < SEQ / 512; ++it)
                ((float4*)y)[h * (SEQ / 8) + it * 64 + lane] = acc[it];
        }

        // wave-total counters via ballot+popcount: one v_cmp per (element,f),
        // accumulate on the scalar pipe, final shuffle reduce deleted.
        // Proven ~1.18x per-wave vs round 0 (rounds 3/4 occupancy-normalized).
        int cnt[NF];
#pragma unroll
        for (int f = 0; f < NF; ++f) cnt[f] = 0;

        // 128-el pair iter: lane handles t=TB+2*lane and t+1; per tap one 2-dword load
#define MRF_ITER2(TB) { \
            const int e0_ = (TB) + 2 * lane - 4 * D; \
            float CvA = 0.0f, CvB = 0.0f; \
            _Pragma("unroll") \
            for (int jj = 0; jj < 9; ++jj) { \
                f32x2u p_ = *(const f32x2u*)(y + e0_ + jj * D); \
                CvA = __builtin_fmaf(w[jj], p_.x, CvA); \
                CvB = __builtin_fmaf(w[jj], p_.y, CvB); \
            } \
            _Pragma("unroll") \
            for (int f = 0; f < NF; ++f) \
                cnt[f] += __popcll(__ballot(CvA > bs[f])) + __popcll(__ballot(CvB > bs[f])); }

        // 64-el unmasked iter
#define MRF_ITER(TB) { \
            const int t_ = (TB) + lane; \
            float Cv = 0.0f; \
            _Pragma("unroll") \
            for (int jj = 0; jj < 9; ++jj) \
                Cv = __builtin_fmaf(w[jj], y[t_ + (jj - 4) * D], Cv); \
            _Pragma("unroll") \
            for (int f = 0; f < NF; ++f) \
                cnt[f] += __popcll(__ballot(Cv > bs[f])); }

        // 64-el boundary iter: per-tap window is WAVE-UNIFORM in/out/straddle ->
        // scalar-branch skip (out), plain fma (in), clamped load only when straddling
#define MRF_MASKED(TB) { \
            const int t_ = (TB) + lane; \
            float Cv = 0.0f; \
            _Pragma("unroll") \
            for (int jj = 0; jj < 9; ++jj) { \
                const int lo_ = (TB) + (jj - 4) * D; \
                if (lo_ >= 0 && lo_ + 63 < SEQ) { \
                    Cv = __builtin_fmaf(w[jj], y[t_ + (jj - 4) * D], Cv); \
                } else if (lo_ + 63 >= 0 && lo_ < SEQ) { \
                    const int u_ = t_ + (jj - 4) * D; \
                    float v_ = y[u_ & (SEQ - 1)]; \
                    v_ = ((unsigned)u_ < (unsigned)SEQ) ? v_ : 0.0f; \
                    Cv = __builtin_fmaf(w[jj], v_, Cv); \
                } \
            } \
            _Pragma("unroll") \
            for (int f = 0; f < NF; ++f) \
                cnt[f] += __popcll(__ballot(Cv > bs[f])); }

        if ((k & 1) == PAD1) {
            // ===== full padded range [0, SEQ): masked lead, paired interior, masked trail =====
#pragma unroll 4
            for (int j = 0; j < JLO; ++j) MRF_MASKED(j * 64)
#pragma unroll 2
            for (int a = 0; a < NI2; ++a) MRF_ITER2(JLO * 64 + a * 128)
            if constexpr (IBR) MRF_ITER(JLO * 64 + NI2 * 128)
#pragma unroll 4
            for (int j = JT0; j < SEQ / 64; ++j) MRF_MASKED(j * 64)
        } else {
            // ===== valid region [P, SEQ-P): paired main, bridge, clamped partial =====
#pragma unroll 2
            for (int a = 0; a < MV2; ++a) MRF_ITER2(P + a * 128)
            if constexpr (TV1) MRF_ITER(P + MV2 * 128)
            if constexpr (REM != 0) {   // final partial, clamped reads, poisoned lanes
                const int t = P + MV2 * 128 + TV1 * 64 + lane;
                const int tr = (t < SEQ - P) ? t : (SEQ - P - 1);
                const float* __restrict__ pb = y + tr - 4 * D;
                float Cv = 0.0f;
#pragma unroll
                for (int jj = 0; jj < 9; ++jj)
                    Cv = __builtin_fmaf(w[jj], pb[jj * D], Cv);
                Cv = (t < SEQ - P) ? Cv : -3.402823466e38f;   // poison -> never > bias
#pragma unroll
                for (int f = 0; f < NF; ++f)
                    cnt[f] += __popcll(__ballot(Cv > bs[f]));
            }
        }

#undef MRF_ITER2
#undef MRF_ITER
#undef MRF_MASKED

        // ---- write (cnt[] is already the wave total; no shuffle reduce) ----
        const bool full = ((k & 1) == PAD1);
        const float invT = full ? (1.0f / (float)SEQ) : (1.0f / (float)RANGE);
        const int pos = full ? ((k - PAD1) >> 1) : (42 + ((k - (1 - PAD1)) >> 1));
        const int colb = CBASE + pos * NF;
        if (lane == 0) {
#pragma unroll
            for (int f = 0; f < NF; ++f)
                out[(size_t)b * NFTOT + colb + f] = (float)cnt[f] * invT;
        }
    }
}

// Occupancy structure (rounds 0-6):
//  - VGPR must stay <=128 (bucket halves at 64/128/256; round-3/4 at 144 ->
//    11% occ, 1.6x slower). amdgpu_num_vgpr(128) + w/bs scalarization holds it.
//  - Round-5 finding: with 1-wave workgroups, residency pinned at ~7 waves/CU
//    (21%) even though VGPR allows 16 -> per-CU WORKGROUP SLOTS are the cap,
//    not VGPR/LDS. Fix: 4-wave workgroups (this round). 4 waves x 8KB private
//    ybuf = 32KB/block -> LDS allows 5 blocks/CU; VGPR allows 16 waves/CU;
//    WG slots no longer bind. Waves stay fully independent (no syncthreads).
//  - Spill sentinel: WRITE_SIZE >> 2.5 MB (round-1: a cap far below demand
//    spilled 400 MB/dispatch; cap at the boundary just above demand only).
extern "C" __global__ void __launch_bounds__(WPB * 64)
__attribute__((amdgpu_num_vgpr(128)))
mrf_kernel(const float* __restrict__ x, const float* __restrict__ kw,
           const float* __restrict__ cc, const float* __restrict__ bias,
           float* __restrict__ out) {
    __shared__ __align__(16) float ybuf[WPB][SEQ];   // 32 KB: 8 KB private per wave

    // XCD-chunked bijective swizzle (proven round 0): XCD x owns a contiguous
    // chunk of (b,i,g) with b slowest -> concurrent blocks on an XCD share ~1-2
    // b values -> x slices stay L2-resident. Round-1 measured the alternative
    // (i slowest): per-XCD working set = all 64 b slices > 4 MB L2 -> 1.75 GB
    // of L2 misses, 1.7x slower.
    constexpr int NGRID = NDIL * NBATCH * NGRP;        // 4992
    constexpr int CHUNK = NGRID / NXCD;                // 624
    const int blk = (blockIdx.x % NXCD) * CHUNK + blockIdx.x / NXCD;

    const int g = blk % NGRP;               // slot group
    const int rest = blk / NGRP;
    const int i = rest % NDIL;              // dilation index
    const int b = rest / NDIL;              // batch index (slowest)
    const int wv = threadIdx.x >> 6;        // wave id within block
    const int lane = threadIdx.x & 63;
    const int s = g * WPB + wv;             // this wave's slot in [0, NSLOT)

    const float* xb = x + (size_t)b * (NCH * SEQ);

    switch (i) {
#define MRF_CASE(I) case I: body<I>(kw, cc, bias, out, xb, ybuf[wv], b, s, lane); break;
        MRF_CASE(0)  MRF_CASE(1)  MRF_CASE(2)  MRF_CASE(3)  MRF_CASE(4)
        MRF_CASE(5)  MRF_CASE(6)  MRF_CASE(7)  MRF_CASE(8)  MRF_CASE(9)
        MRF_CASE(10) MRF_CASE(11) MRF_CASE(12) MRF_CASE(13) MRF_CASE(14)
        MRF_CASE(15) MRF_CASE(16) MRF_CASE(17) MRF_CASE(18) MRF_CASE(19)
        MRF_CASE(20) MRF_CASE(21) MRF_CASE(22) MRF_CASE(23) MRF_CASE(24)
        MRF_CASE(25)
#undef MRF_CASE
    }
}

extern "C" void kernel_launch(void* const* d_in, const int* in_sizes, int n_in,
                              void* d_out, int out_size, void* d_ws, size_t ws_size,
                              hipStream_t stream) {
    (void)in_sizes; (void)n_in; (void)d_ws; (void)ws_size; (void)out_size;
    const float* x    = (const float*)d_in[0];
    const float* kw   = (const float*)d_in[1];
    const float* cc   = (const float*)d_in[2];
    const float* bias = (const float*)d_in[3];
    float* out = (float*)d_out;

    mrf_kernel<<<dim3(NDIL * NBATCH * NGRP), dim3(WPB * 64), 0, stream>>>(x, kw, cc, bias, out);
}

// Round 8
// 398.484 us; speedup vs baseline: 1.1921x; 1.1921x over previous
//
#include <hip/hip_runtime.h>

#define NKER 84
#define NCH 9
#define SEQ 2048
#define NBATCH 64
#define NDIL 26
#define NFTOT 9996
#define MAXNF 15
#define NSLOT 28
#define NXCD 8

// Static MiniRocket config for SEQ_LEN=2048, NUM_FEATURES=10000 (replicates numpy float64 logspace)
static constexpr int DILS[NDIL]   = {1,2,3,4,5,7,8,10,12,14,17,20,25,29,35,42,51,61,73,87,104,125,149,178,213,255};
static constexpr int NFDS[NDIL]   = {15,12,4,4,8,4,4,4,4,4,4,4,4,4,4,4,4,4,3,3,3,3,3,3,3,3};
static constexpr int CBASES[NDIL] = {0,1260,2268,2604,2940,3612,3948,4284,4620,4956,5292,5628,5964,6300,6636,6972,7308,7644,7980,8232,8484,8736,8988,9240,9492,9744};

// 2-float vector with 4-byte alignment: legal at odd dword offsets; compiler
// emits ds_read_b64 (aligned) or ds_read2_b32 (unaligned) — one DS instruction
// for two consecutive taps' elements either way.
typedef float f32x2u __attribute__((ext_vector_type(2), aligned(4)));

// Force a (known-uniform) float into an SGPR. Scalar v_fma/v_cmp accept one
// SGPR operand at full rate, so wave-uniform constants (w, bias) cost 0 VGPRs.
// NOTE (round-7 lesson): packed VOP3P f32 ops (v_pk_fma_f32/v_pk_add_f32) do
// NOT accept SGPR sources on gfx950 — scalarized weights only work for the
// scalar-FMA conv path. Packed conv was tried and abandoned (compile fail;
// the all-VGPR rewrites cost more than they save).
__device__ __forceinline__ float uniform_f(float v) {
    return __builtin_bit_cast(float, __builtin_amdgcn_readfirstlane(__builtin_bit_cast(int, v)));
}

// Packed f32 add, all-VGPR operands (legal VOP3P form on gfx950):
// 2 floats/lane/instruction for the y-build accumulation.
__device__ __forceinline__ f32x2u pk_add(f32x2u a, f32x2u b) {
    f32x2u d;
    asm("v_pk_add_f32 %0, %1, %2" : "=v"(d) : "v"(a), "v"(b));
    return d;
}

template <int I>
__device__ __forceinline__ void body(const float* __restrict__ kw,
                                     const float* __restrict__ cc,
                                     const float* __restrict__ bias,
                                     float* __restrict__ out,
                                     const float* __restrict__ xb,   // x + b*NCH*SEQ
                                     float* __restrict__ y,
                                     int b, int slot, int lane) {
    constexpr int D = DILS[I];
    constexpr int NF = NFDS[I];
    constexpr int P = 4 * D;
    constexpr int PAD1 = I & 1;
    constexpr int CBASE = CBASES[I];
    constexpr int RANGE = SEQ - 2 * P;          // valid-region length (>0 for all D)
    // full-range loop split (compile-time): interior j has all taps in [0, SEQ) for every lane
    constexpr int JLO = (P + 63) / 64;                      // first fully-interior 64-iter
    constexpr int JHI = (SEQ - P - 64) / 64;                // last fully-interior 64-iter (incl)
    constexpr int NI  = (JHI + 1 > JLO) ? (JHI + 1 - JLO) : 0;   // # interior 64-iters
    constexpr int NI2 = NI / 2;                             // 128-el pair-iters
    constexpr bool IBR = (NI & 1) != 0;                     // one bridge 64-iter
    constexpr int JT0 = (JHI + 1 > JLO) ? (JHI + 1) : JLO;  // start of trailing boundary
    // valid-region decomposition: pairs + optional 64-bridge + clamped partial
    constexpr int MV2 = RANGE / 128;
    constexpr int TV1 = (RANGE - MV2 * 128) / 64;           // 0 or 1
    constexpr int REM = RANGE - MV2 * 128 - TV1 * 64;       // 0..63

    const float4* __restrict__ xb4 = (const float4*)xb;     // [NCH][SEQ/4]

    for (int k = slot; k < NKER; k += NSLOT) {
        // ---- per-kernel config (wave-uniform scalars) ----
        int mb = 0;
        for (int c = 0; c < NCH; ++c)
            if (cc[(I * NCH + c) * NKER + k] != 0.0f) mb |= (1 << c);
        mb = __builtin_amdgcn_readfirstlane(mb);

        int j0 = -1, j1 = -1, j2 = -1, no = 0;
        for (int j = 0; j < 9; ++j) {
            if (kw[k * 9 + j] > 0.0f) {
                if (no == 0) j0 = j; else if (no == 1) j1 = j; else j2 = j;
                ++no;
            }
        }
        j0 = __builtin_amdgcn_readfirstlane(j0);
        j1 = __builtin_amdgcn_readfirstlane(j1);
        j2 = __builtin_amdgcn_readfirstlane(j2);

        // tap weights and bias thresholds: wave-uniform -> SGPRs
        // (rounds 3-5: keeps the allocator under the 128-VGPR occupancy boundary).
        float w[9];
#pragma unroll
        for (int jj = 0; jj < 9; ++jj)
            w[jj] = uniform_f((jj == j0 || jj == j1 || jj == j2) ? 2.0f : -1.0f);

        float bs[NF];
#pragma unroll
        for (int f = 0; f < NF; ++f)
            bs[f] = uniform_f(bias[(I * NKER + k) * MAXNF + f]);

        // ---- build y[t] = sum of masked channels, two half-SEQ passes ----
        // packed adds: 2 v_pk_add_f32 per float4 instead of 4 v_add_f32
#pragma unroll
        for (int h = 0; h < 2; ++h) {
            f32x2u acc2[2 * (SEQ / 512)];
#pragma unroll
            for (int it = 0; it < 2 * (SEQ / 512); ++it)
                acc2[it] = (f32x2u){0.f, 0.f};
#pragma unroll
            for (int c = 0; c < NCH; ++c) {
                if (mb & (1 << c)) {
#pragma unroll
                    for (int it = 0; it < SEQ / 512; ++it) {
                        float4 v = xb4[c * (SEQ / 4) + h * (SEQ / 8) + it * 64 + lane];
                        acc2[2 * it]     = pk_add(acc2[2 * it],     (f32x2u){v.x, v.y});
                        acc2[2 * it + 1] = pk_add(acc2[2 * it + 1], (f32x2u){v.z, v.w});
                    }
                }
            }
#pragma unroll
            for (int it = 0; it < SEQ / 512; ++it)
                ((float4*)y)[h * (SEQ / 8) + it * 64 + lane] =
                    make_float4(acc2[2 * it].x, acc2[2 * it].y,
                                acc2[2 * it + 1].x, acc2[2 * it + 1].y);
        }

        // wave-total counters via ballot+popcount: one v_cmp per (element,f),
        // accumulate on the scalar pipe, final shuffle reduce deleted.
        int cnt[NF];
#pragma unroll
        for (int f = 0; f < NF; ++f) cnt[f] = 0;

        // 128-el pair iter: lane handles t=TB+2*lane and t+1; per tap one
        // 2-dword LDS load feeding two independent scalar FMA chains.
#define MRF_ITER2(TB) { \
            const int e0_ = (TB) + 2 * lane - 4 * D; \
            float CvA = 0.0f, CvB = 0.0f; \
            _Pragma("unroll") \
            for (int jj = 0; jj < 9; ++jj) { \
                f32x2u p_ = *(const f32x2u*)(y + e0_ + jj * D); \
                CvA = __builtin_fmaf(w[jj], p_.x, CvA); \
                CvB = __builtin_fmaf(w[jj], p_.y, CvB); \
            } \
            _Pragma("unroll") \
            for (int f = 0; f < NF; ++f) \
                cnt[f] += __popcll(__ballot(CvA > bs[f])) + __popcll(__ballot(CvB > bs[f])); }

        // 64-el unmasked iter
#define MRF_ITER(TB) { \
            const int t_ = (TB) + lane; \
            float Cv = 0.0f; \
            _Pragma("unroll") \
            for (int jj = 0; jj < 9; ++jj) \
                Cv = __builtin_fmaf(w[jj], y[t_ + (jj - 4) * D], Cv); \
            _Pragma("unroll") \
            for (int f = 0; f < NF; ++f) \
                cnt[f] += __popcll(__ballot(Cv > bs[f])); }

        // 64-el boundary iter. Callers FULLY unroll so TB is compile-time and
        // the per-tap in/out/straddle classification folds: out-of-window taps
        // emit nothing, in-window taps a plain fma, straddling taps the clamped
        // load. (For D=213/255 the whole full-range pass is boundary iters;
        // folding deletes ~4/9 taps and all branch overhead there.)
#define MRF_MASKED(TB) { \
            const int t_ = (TB) + lane; \
            float Cv = 0.0f; \
            _Pragma("unroll") \
            for (int jj = 0; jj < 9; ++jj) { \
                const int lo_ = (TB) + (jj - 4) * D; \
                if (lo_ >= 0 && lo_ + 63 < SEQ) { \
                    Cv = __builtin_fmaf(w[jj], y[t_ + (jj - 4) * D], Cv); \
                } else if (lo_ + 63 >= 0 && lo_ < SEQ) { \
                    const int u_ = t_ + (jj - 4) * D; \
                    float v_ = y[u_ & (SEQ - 1)]; \
                    v_ = ((unsigned)u_ < (unsigned)SEQ) ? v_ : 0.0f; \
                    Cv = __builtin_fmaf(w[jj], v_, Cv); \
                } \
            } \
            _Pragma("unroll") \
            for (int f = 0; f < NF; ++f) \
                cnt[f] += __popcll(__ballot(Cv > bs[f])); }

        if ((k & 1) == PAD1) {
            // ===== full padded range [0, SEQ): masked lead, paired interior, masked trail =====
#pragma unroll
            for (int j = 0; j < JLO; ++j) MRF_MASKED(j * 64)
#pragma unroll 2
            for (int a = 0; a < NI2; ++a) MRF_ITER2(JLO * 64 + a * 128)
            if constexpr (IBR) MRF_ITER(JLO * 64 + NI2 * 128)
#pragma unroll
            for (int j = JT0; j < SEQ / 64; ++j) MRF_MASKED(j * 64)
        } else {
            // ===== valid region [P, SEQ-P): paired main, bridge, clamped partial =====
#pragma unroll 2
            for (int a = 0; a < MV2; ++a) MRF_ITER2(P + a * 128)
            if constexpr (TV1) MRF_ITER(P + MV2 * 128)
            if constexpr (REM != 0) {   // final partial, clamped reads, poisoned lanes
                const int t = P + MV2 * 128 + TV1 * 64 + lane;
                const int tr = (t < SEQ - P) ? t : (SEQ - P - 1);
                const float* __restrict__ pb = y + tr - 4 * D;
                float Cv = 0.0f;
#pragma unroll
                for (int jj = 0; jj < 9; ++jj)
                    Cv = __builtin_fmaf(w[jj], pb[jj * D], Cv);
                Cv = (t < SEQ - P) ? Cv : -3.402823466e38f;   // poison -> never > bias
#pragma unroll
                for (int f = 0; f < NF; ++f)
                    cnt[f] += __popcll(__ballot(Cv > bs[f]));
            }
        }

#undef MRF_ITER2
#undef MRF_ITER
#undef MRF_MASKED

        // ---- write (cnt[] is already the wave total; no shuffle reduce) ----
        const bool full = ((k & 1) == PAD1);
        const float invT = full ? (1.0f / (float)SEQ) : (1.0f / (float)RANGE);
        const int pos = full ? ((k - PAD1) >> 1) : (42 + ((k - (1 - PAD1)) >> 1));
        const int colb = CBASE + pos * NF;
        if (lane == 0) {
#pragma unroll
            for (int f = 0; f < NF; ++f)
                out[(size_t)b * NFTOT + colb + f] = (float)cnt[f] * invT;
        }
    }
}

// Occupancy ledger (rounds 0-7):
//  - VGPR <=128 mandatory (bucket halves at 64/128/256; 144 VGPR -> 11% occ,
//    1.6x slower). amdgpu_num_vgpr(128) + w/bs scalarization holds it with a
//    tolerable ~3MB spill. Spill sentinel: WRITE_SIZE >> 5.5 MB.
//  - Residency pins at ~6.7-7 waves/CU at VGPR=128 for BOTH 1-wave (R5) and
//    4-wave (R6) workgroups -> not a WG-slot cap; occupancy lever exhausted.
//    R6's 4-wave geometry also spilled more (9MB) -> stay 1-wave.
//  - R7: VOP3P packed-f32 takes VGPR sources only; SGPR-weight pk_fma illegal.
//  - NSLOT=28 (3 k/block): per-k work is self-contained, so finer blocks add
//    no redundant work and cut tail imbalance (~11 -> ~26 shorter rounds).
extern "C" __global__ void __launch_bounds__(64)
__attribute__((amdgpu_num_vgpr(128)))
mrf_kernel(const float* __restrict__ x, const float* __restrict__ kw,
           const float* __restrict__ cc, const float* __restrict__ bias,
           float* __restrict__ out) {
    __shared__ __align__(16) float ybuf[SEQ];   // 8 KB per 1-wave block

    // XCD-chunked bijective swizzle (proven round 0): XCD x owns a contiguous
    // chunk of (b,i,s) with b slowest -> concurrent blocks on an XCD share ~1-2
    // b values -> x slices stay L2-resident. Round-1 measured the alternative
    // (i slowest): per-XCD working set = all 64 b slices > 4 MB L2 -> 1.75 GB
    // of L2 misses, 1.7x slower.
    constexpr int NGRID = NDIL * NBATCH * NSLOT;       // 46592
    constexpr int CHUNK = NGRID / NXCD;                // 5824
    const int blk = (blockIdx.x % NXCD) * CHUNK + blockIdx.x / NXCD;

    const int s = blk % NSLOT;
    const int rest = blk / NSLOT;
    const int i = rest % NDIL;              // dilation index
    const int b = rest / NDIL;              // batch index (slowest)
    const int lane = threadIdx.x & 63;

    const float* xb = x + (size_t)b * (NCH * SEQ);

    switch (i) {
#define MRF_CASE(I) case I: body<I>(kw, cc, bias, out, xb, ybuf, b, s, lane); break;
        MRF_CASE(0)  MRF_CASE(1)  MRF_CASE(2)  MRF_CASE(3)  MRF_CASE(4)
        MRF_CASE(5)  MRF_CASE(6)  MRF_CASE(7)  MRF_CASE(8)  MRF_CASE(9)
        MRF_CASE(10) MRF_CASE(11) MRF_CASE(12) MRF_CASE(13) MRF_CASE(14)
        MRF_CASE(15) MRF_CASE(16) MRF_CASE(17) MRF_CASE(18) MRF_CASE(19)
        MRF_CASE(20) MRF_CASE(21) MRF_CASE(22) MRF_CASE(23) MRF_CASE(24)
        MRF_CASE(25)
#undef MRF_CASE
    }
}

extern "C" void kernel_launch(void* const* d_in, const int* in_sizes, int n_in,
                              void* d_out, int out_size, void* d_ws, size_t ws_size,
                              hipStream_t stream) {
    (void)in_sizes; (void)n_in; (void)d_ws; (void)ws_size; (void)out_size;
    const float* x    = (const float*)d_in[0];
    const float* kw   = (const float*)d_in[1];
    const float* cc   = (const float*)d_in[2];
    const float* bias = (const float*)d_in[3];
    float* out = (float*)d_out;

    mrf_kernel<<<dim3(NDIL * NBATCH * NSLOT), dim3(64), 0, stream>>>(x, kw, cc, bias, out);
}

// Round 9
// 316.928 us; speedup vs baseline: 1.4989x; 1.2573x over previous
//
#include <hip/hip_runtime.h>

#define NKER 84
#define NCH 9
#define SEQ 2048
#define NBATCH 64
#define NDIL 26
#define NFTOT 9996
#define MAXNF 15
#define NSLOT 28
#define NXCD 8

// Static MiniRocket config for SEQ_LEN=2048, NUM_FEATURES=10000 (replicates numpy float64 logspace)
static constexpr int DILS[NDIL]   = {1,2,3,4,5,7,8,10,12,14,17,20,25,29,35,42,51,61,73,87,104,125,149,178,213,255};
static constexpr int NFDS[NDIL]   = {15,12,4,4,8,4,4,4,4,4,4,4,4,4,4,4,4,4,3,3,3,3,3,3,3,3};
static constexpr int CBASES[NDIL] = {0,1260,2268,2604,2940,3612,3948,4284,4620,4956,5292,5628,5964,6300,6636,6972,7308,7644,7980,8232,8484,8736,8988,9240,9492,9744};

// 2-float vector with 4-byte alignment: legal at odd dword offsets; compiler
// emits ds_read_b64 (aligned) or ds_read2_b32 (unaligned) — one DS instruction
// for two consecutive taps' elements either way.
typedef float f32x2u __attribute__((ext_vector_type(2), aligned(4)));

// Force a (known-uniform) float into an SGPR. Scalar v_fma/v_cmp accept one
// SGPR operand at full rate, so wave-uniform constants (w, bias) cost 0 VGPRs.
// R7 lesson: VOP3P packed-f32 (pk_fma/pk_add) takes VGPR sources ONLY.
__device__ __forceinline__ float uniform_f(float v) {
    return __builtin_bit_cast(float, __builtin_amdgcn_readfirstlane(__builtin_bit_cast(int, v)));
}

// Packed f32 add, all-VGPR operands (legal VOP3P form on gfx950).
__device__ __forceinline__ f32x2u pk_add(f32x2u a, f32x2u b) {
    f32x2u d;
    asm("v_pk_add_f32 %0, %1, %2" : "=v"(d) : "v"(a), "v"(b));
    return d;
}

template <int I>
__device__ __forceinline__ void body(const float* __restrict__ kw,
                                     const float* __restrict__ cc,
                                     const float* __restrict__ bias,
                                     float* __restrict__ out,
                                     const float* __restrict__ xb,   // x + b*NCH*SEQ
                                     float* __restrict__ y,          // 8KB ybuf SHARED by both waves
                                     int* __restrict__ cbuf,         // NF-int merge buffer
                                     int b, int slot, int lane, int wv) {
    constexpr int D = DILS[I];
    constexpr int NF = NFDS[I];
    constexpr int P = 4 * D;
    constexpr int PAD1 = I & 1;
    constexpr int CBASE = CBASES[I];
    constexpr int RANGE = SEQ - 2 * P;          // valid-region length (>0 for all D)
    // full-range loop split (compile-time): interior j has all taps in [0, SEQ) for every lane
    constexpr int JLO = (P + 63) / 64;                      // first fully-interior 64-iter
    constexpr int JHI = (SEQ - P - 64) / 64;                // last fully-interior 64-iter (incl)
    constexpr int NI  = (JHI + 1 > JLO) ? (JHI + 1 - JLO) : 0;   // # interior 64-iters
    constexpr int NI2 = NI / 2;                             // 128-el pair-iters
    constexpr bool IBR = (NI & 1) != 0;                     // one bridge 64-iter
    constexpr int JT0 = (JHI + 1 > JLO) ? (JHI + 1) : JLO;  // start of trailing boundary
    // valid-region decomposition: pairs + optional 64-bridge + clamped partial
    constexpr int MV2 = RANGE / 128;
    constexpr int TV1 = (RANGE - MV2 * 128) / 64;           // 0 or 1
    constexpr int REM = RANGE - MV2 * 128 - TV1 * 64;       // 0..63

    const float4* __restrict__ xb4 = (const float4*)xb;     // [NCH][SEQ/4]

    for (int k = slot; k < NKER; k += NSLOT) {
        // barrier A: previous k's conv reads + merge reads are done before
        // this k's build overwrites ybuf (and before wave1 re-writes cbuf).
        __syncthreads();

        // ---- per-kernel config (wave-uniform scalars, duplicated per wave) ----
        int mb = 0;
        for (int c = 0; c < NCH; ++c)
            if (cc[(I * NCH + c) * NKER + k] != 0.0f) mb |= (1 << c);
        mb = __builtin_amdgcn_readfirstlane(mb);

        int j0 = -1, j1 = -1, j2 = -1, no = 0;
        for (int j = 0; j < 9; ++j) {
            if (kw[k * 9 + j] > 0.0f) {
                if (no == 0) j0 = j; else if (no == 1) j1 = j; else j2 = j;
                ++no;
            }
        }
        j0 = __builtin_amdgcn_readfirstlane(j0);
        j1 = __builtin_amdgcn_readfirstlane(j1);
        j2 = __builtin_amdgcn_readfirstlane(j2);

        // tap weights and bias thresholds: wave-uniform -> SGPRs
        // (rounds 3-5: keeps the allocator under the 128-VGPR occupancy boundary).
        float w[9];
#pragma unroll
        for (int jj = 0; jj < 9; ++jj)
            w[jj] = uniform_f((jj == j0 || jj == j1 || jj == j2) ? 2.0f : -1.0f);

        float bs[NF];
#pragma unroll
        for (int f = 0; f < NF; ++f)
            bs[f] = uniform_f(bias[(I * NKER + k) * MAXNF + f]);

        // ---- build y[t]: wave wv builds half h=wv (halves build latency too) ----
        {
            const int h = wv;
            f32x2u acc2[2 * (SEQ / 512)];
#pragma unroll
            for (int it = 0; it < 2 * (SEQ / 512); ++it)
                acc2[it] = (f32x2u){0.f, 0.f};
#pragma unroll
            for (int c = 0; c < NCH; ++c) {
                if (mb & (1 << c)) {
#pragma unroll
                    for (int it = 0; it < SEQ / 512; ++it) {
                        float4 v = xb4[c * (SEQ / 4) + h * (SEQ / 8) + it * 64 + lane];
                        acc2[2 * it]     = pk_add(acc2[2 * it],     (f32x2u){v.x, v.y});
                        acc2[2 * it + 1] = pk_add(acc2[2 * it + 1], (f32x2u){v.z, v.w});
                    }
                }
            }
#pragma unroll
            for (int it = 0; it < SEQ / 512; ++it)
                ((float4*)y)[h * (SEQ / 8) + it * 64 + lane] =
                    make_float4(acc2[2 * it].x, acc2[2 * it].y,
                                acc2[2 * it + 1].x, acc2[2 * it + 1].y);
        }
        // barrier B: both halves of y visible before conv reads cross-half taps
        __syncthreads();

        // wave-total counters via ballot+popcount (scalar-pipe accumulate)
        int cnt[NF];
#pragma unroll
        for (int f = 0; f < NF; ++f) cnt[f] = 0;

#define MRF_ITER2(TB) { \
            const int e0_ = (TB) + 2 * lane - 4 * D; \
            float CvA = 0.0f, CvB = 0.0f; \
            _Pragma("unroll") \
            for (int jj = 0; jj < 9; ++jj) { \
                f32x2u p_ = *(const f32x2u*)(y + e0_ + jj * D); \
                CvA = __builtin_fmaf(w[jj], p_.x, CvA); \
                CvB = __builtin_fmaf(w[jj], p_.y, CvB); \
            } \
            _Pragma("unroll") \
            for (int f = 0; f < NF; ++f) \
                cnt[f] += __popcll(__ballot(CvA > bs[f])) + __popcll(__ballot(CvB > bs[f])); }

#define MRF_ITER(TB) { \
            const int t_ = (TB) + lane; \
            float Cv = 0.0f; \
            _Pragma("unroll") \
            for (int jj = 0; jj < 9; ++jj) \
                Cv = __builtin_fmaf(w[jj], y[t_ + (jj - 4) * D], Cv); \
            _Pragma("unroll") \
            for (int f = 0; f < NF; ++f) \
                cnt[f] += __popcll(__ballot(Cv > bs[f])); }

        // boundary iter: callers fully unroll -> per-tap window tests fold
#define MRF_MASKED(TB) { \
            const int t_ = (TB) + lane; \
            float Cv = 0.0f; \
            _Pragma("unroll") \
            for (int jj = 0; jj < 9; ++jj) { \
                const int lo_ = (TB) + (jj - 4) * D; \
                if (lo_ >= 0 && lo_ + 63 < SEQ) { \
                    Cv = __builtin_fmaf(w[jj], y[t_ + (jj - 4) * D], Cv); \
                } else if (lo_ + 63 >= 0 && lo_ < SEQ) { \
                    const int u_ = t_ + (jj - 4) * D; \
                    float v_ = y[u_ & (SEQ - 1)]; \
                    v_ = ((unsigned)u_ < (unsigned)SEQ) ? v_ : 0.0f; \
                    Cv = __builtin_fmaf(w[jj], v_, Cv); \
                } \
            } \
            _Pragma("unroll") \
            for (int f = 0; f < NF; ++f) \
                cnt[f] += __popcll(__ballot(Cv > bs[f])); }

        // ---- conv: waves split the t-range into disjoint alternating chunks ----
        if ((k & 1) == PAD1) {
            // full padded range [0, SEQ): masked lead + paired interior + masked trail
#pragma unroll
            for (int j = 0; j < JLO; ++j)
                if (((j >> 1) & 1) == wv) MRF_MASKED(j * 64)
#pragma unroll 2
            for (int a = wv; a < NI2; a += 2) MRF_ITER2(JLO * 64 + a * 128)
            if constexpr (IBR)
                if ((NI2 & 1) == wv) MRF_ITER(JLO * 64 + NI2 * 128)
#pragma unroll
            for (int j = JT0; j < SEQ / 64; ++j)
                if (((j >> 1) & 1) == wv) MRF_MASKED(j * 64)
        } else {
            // valid region [P, SEQ-P): paired main + bridge + clamped partial
#pragma unroll 2
            for (int a = wv; a < MV2; a += 2) MRF_ITER2(P + a * 128)
            if constexpr (TV1)
                if ((MV2 & 1) == wv) MRF_ITER(P + MV2 * 128)
            if constexpr (REM != 0) {
                if (((MV2 + TV1) & 1) == wv) {
                    const int t = P + MV2 * 128 + TV1 * 64 + lane;
                    const int tr = (t < SEQ - P) ? t : (SEQ - P - 1);
                    const float* __restrict__ pb = y + tr - 4 * D;
                    float Cv = 0.0f;
#pragma unroll
                    for (int jj = 0; jj < 9; ++jj)
                        Cv = __builtin_fmaf(w[jj], pb[jj * D], Cv);
                    Cv = (t < SEQ - P) ? Cv : -3.402823466e38f;  // poison -> never > bias
#pragma unroll
                    for (int f = 0; f < NF; ++f)
                        cnt[f] += __popcll(__ballot(Cv > bs[f]));
                }
            }
        }

#undef MRF_ITER2
#undef MRF_ITER
#undef MRF_MASKED

        // ---- merge the two waves' counts, wave0 writes out ----
        if (wv == 1 && lane == 0) {
#pragma unroll
            for (int f = 0; f < NF; ++f) cbuf[f] = cnt[f];
        }
        // barrier C: cbuf visible to wave0
        __syncthreads();
        if (wv == 0 && lane == 0) {
            const bool full = ((k & 1) == PAD1);
            const float invT = full ? (1.0f / (float)SEQ) : (1.0f / (float)RANGE);
            const int pos = full ? ((k - PAD1) >> 1) : (42 + ((k - (1 - PAD1)) >> 1));
            const int colb = CBASE + pos * NF;
#pragma unroll
            for (int f = 0; f < NF; ++f)
                out[(size_t)b * NFTOT + colb + f] = (float)(cnt[f] + cbuf[f]) * invT;
        }
    }
}

// Residency ledger (rounds 0-9):
//  - VGPR <=128 mandatory (bucket halves above 128: R3/R4 at 144 -> half the
//    waves, 1.6x slower). amdgpu_num_vgpr(128) + w/bs scalarization holds it.
//  - R6 killed the WG-slot theory (4-wave WGs gave the SAME ~6-8 waves/CU).
//    One-parameter fit for R5+R6: effective LDS pool ~64KB/CU ->
//    waves/CU = 64KB / (LDS per wave). R9 therefore HALVES LDS/wave by
//    sharing one 8KB ybuf between 2 waves (cooperative build, disjoint
//    t-range conv, tiny count merge). Discriminating experiment: if
//    occupancy stays ~22% the cap is a hard ~8-wave/CU limit instead.
//  - Spill sentinel: WRITE_SIZE >> ~2x expected (R1: 400 MB catastrophe).
extern "C" __global__ void __launch_bounds__(128)
__attribute__((amdgpu_num_vgpr(128)))
mrf_kernel(const float* __restrict__ x, const float* __restrict__ kw,
           const float* __restrict__ cc, const float* __restrict__ bias,
           float* __restrict__ out) {
    __shared__ __align__(16) float ybuf[SEQ];   // 8KB, shared by the 2 waves
    __shared__ int cbuf[MAXNF];                 // wave1 -> wave0 count merge

    // XCD-chunked bijective swizzle (proven round 0): XCD x owns a contiguous
    // chunk of (b,i,s) with b slowest -> concurrent blocks on an XCD share ~1-2
    // b values -> x slices stay L2-resident. (R1 measured the alternative:
    // i slowest -> 1.75 GB of L2 misses, 1.7x slower.)
    constexpr int NGRID = NDIL * NBATCH * NSLOT;       // 46592
    constexpr int CHUNK = NGRID / NXCD;                // 5824
    const int blk = (blockIdx.x % NXCD) * CHUNK + blockIdx.x / NXCD;

    const int s = blk % NSLOT;
    const int rest = blk / NSLOT;
    const int i = rest % NDIL;              // dilation index
    const int b = rest / NDIL;              // batch index (slowest)
    const int lane = threadIdx.x & 63;
    // wave id, forced to SGPR so work-split guards are scalar branches
    const int wv = __builtin_amdgcn_readfirstlane((int)(threadIdx.x >> 6));

    const float* xb = x + (size_t)b * (NCH * SEQ);

    switch (i) {
#define MRF_CASE(I) case I: body<I>(kw, cc, bias, out, xb, ybuf, cbuf, b, s, lane, wv); break;
        MRF_CASE(0)  MRF_CASE(1)  MRF_CASE(2)  MRF_CASE(3)  MRF_CASE(4)
        MRF_CASE(5)  MRF_CASE(6)  MRF_CASE(7)  MRF_CASE(8)  MRF_CASE(9)
        MRF_CASE(10) MRF_CASE(11) MRF_CASE(12) MRF_CASE(13) MRF_CASE(14)
        MRF_CASE(15) MRF_CASE(16) MRF_CASE(17) MRF_CASE(18) MRF_CASE(19)
        MRF_CASE(20) MRF_CASE(21) MRF_CASE(22) MRF_CASE(23) MRF_CASE(24)
        MRF_CASE(25)
#undef MRF_CASE
    }
}

extern "C" void kernel_launch(void* const* d_in, const int* in_sizes, int n_in,
                              void* d_out, int out_size, void* d_ws, size_t ws_size,
                              hipStream_t stream) {
    (void)in_sizes; (void)n_in; (void)d_ws; (void)ws_size; (void)out_size;
    const float* x    = (const float*)d_in[0];
    const float* kw   = (const float*)d_in[1];
    const float* cc   = (const float*)d_in[2];
    const float* bias = (const float*)d_in[3];
    float* out = (float*)d_out;

    mrf_kernel<<<dim3(NDIL * NBATCH * NSLOT), dim3(128), 0, stream>>>(x, kw, cc, bias, out);
}